// Round 2
// baseline (423.801 us; speedup 1.0000x reference)
//
#include <hip/hip_runtime.h>
#include <float.h>
#include <math.h>

// Problem constants
#define B_    256
#define N_    197
#define C_    768
#define POOL_ 1024
#define LEN_  8
#define TOPK_ 8
#define PROWS (POOL_*LEN_)          // 8192 projected pool rows
#define OUTROWS 261                 // 1 + 64 + 196

typedef __attribute__((ext_vector_type(8))) short short8_t;
typedef __attribute__((ext_vector_type(4))) float f32x4;

// ---------------- workspace layout (byte offsets, 256-aligned) --------------
static const size_t OFF_XMEAN = 0;          //  256*768*4  =   786432
static const size_t OFF_INVX  = 786432;     //  256*4      =     1024
static const size_t OFF_INVP  = 787456;     // 1024*4      =     4096
static const size_t OFF_SIM   = 791552;     // 256*1024*4  =  1048576
static const size_t OFF_ACC   = 1840128;    // [0]=sim sum (f32), [1]=block counter (i32)
static const size_t OFF_ABF   = 1840384;    // 8192*768*2  = 12582912
static const size_t OFF_WBF   = 14423296;   //  768*768*2  =  1179648
static const size_t OFF_PROJ  = 15602944;   // 8192*768*4  = 25165824 -> ends 40768768
// total ~40.8 MB

__device__ __forceinline__ unsigned short f2bf(float f) {
    unsigned int u = __float_as_uint(f);
    u += 0x7fffu + ((u >> 16) & 1u);              // round-to-nearest-even
    return (unsigned short)(u >> 16);
}

// ---------------- Kernel A: mean+copy | pkey inv-norm | bf16 convert --------
// 768 threads/block. All three roles are mutually independent:
//   bid [0,256):       fused mean-pool + concat copy + row inv-L2-norm (invx)
//   bid [256,1280):    prompt_key row inv-L2-norm (invp) -- 1024 floats, no pnorm matrix
//   bid [1280,3520):   fp32 -> bf16 convert of prompt + proj_w
__global__ __launch_bounds__(768) void kA(const float* __restrict__ x,
                                          const float* __restrict__ pkey,
                                          const float* __restrict__ prompt,
                                          const float* __restrict__ projw,
                                          float* __restrict__ out,
                                          float* __restrict__ xmean,
                                          float* __restrict__ invx,
                                          float* __restrict__ invp,
                                          unsigned short* __restrict__ Abf,
                                          unsigned short* __restrict__ Wbf,
                                          float* __restrict__ accum) {
    __shared__ f32x4 red[4][192];    // 12 KB
    __shared__ float sq[256];
    __shared__ float wsum[12];
    const int bid = blockIdx.x, t = threadIdx.x;

    if (bid < B_) {
        // ---- mean + copy + invx (one block per batch row, 12 waves) ----
        const int b = bid;
        const int r = t / 192;                  // 0..3 (row phase, n % 4)
        const int c = t - r * 192;              // float4 column 0..191
        const f32x4* xin  = (const f32x4*)x   + (size_t)b * (N_ * 192) + c;
        f32x4*       outb = (f32x4*)out       + (size_t)b * (OUTROWS * 192) + c;
        float sx = 0.f, sy = 0.f, sz = 0.f, sw = 0.f;
        #pragma unroll 7
        for (int n = r; n < 196; n += 4) {
            f32x4 v = __builtin_nontemporal_load(&xin[(size_t)n * 192]);
            sx += v.x; sy += v.y; sz += v.z; sw += v.w;
            int orow = (n == 0) ? 0 : (64 + n);
            __builtin_nontemporal_store(v, &outb[(size_t)orow * 192]);
        }
        if (r == 0) {                           // row 196 remainder
            f32x4 v = __builtin_nontemporal_load(&xin[(size_t)196 * 192]);
            sx += v.x; sy += v.y; sz += v.z; sw += v.w;
            __builtin_nontemporal_store(v, &outb[(size_t)260 * 192]);
        }
        f32x4 s; s.x = sx; s.y = sy; s.z = sz; s.w = sw;
        red[r][c] = s;
        if (t < 256) sq[t] = 0.f;
        __syncthreads();
        if (r == 0) {                           // threads 0..191 finish mean
            f32x4 a = red[0][c], b2 = red[1][c], c2 = red[2][c], d = red[3][c];
            const float inv = 1.0f / (float)N_;
            f32x4 m;
            m.x = (a.x + b2.x + c2.x + d.x) * inv;
            m.y = (a.y + b2.y + c2.y + d.y) * inv;
            m.z = (a.z + b2.z + c2.z + d.z) * inv;
            m.w = (a.w + b2.w + c2.w + d.w) * inv;
            ((f32x4*)xmean)[b * 192 + c] = m;
            sq[c] = m.x*m.x + m.y*m.y + m.z*m.z + m.w*m.w;
        }
        __syncthreads();
        for (int off = 128; off > 0; off >>= 1) {
            if (t < off) sq[t] += sq[t + off];
            __syncthreads();
        }
        if (t == 0) {
            invx[b] = 1.0f / sqrtf(fmaxf(sq[0], 1e-12f));
            if (b == 0) { accum[0] = 0.0f; ((int*)accum)[1] = 0; }  // ws is poisoned
        }
    } else if (bid < B_ + POOL_) {
        // ---- invp: one pool-key row per block ----
        const int p = bid - B_;
        float v = pkey[(size_t)p * C_ + t];
        float sg = v * v;
        #pragma unroll
        for (int off = 32; off > 0; off >>= 1) sg += __shfl_down(sg, off);
        const int wave = t >> 6;
        if ((t & 63) == 0) wsum[wave] = sg;
        __syncthreads();
        if (t == 0) {
            float tot = wsum[0];
            #pragma unroll
            for (int w = 1; w < 12; ++w) tot += wsum[w];
            invp[p] = 1.0f / sqrtf(fmaxf(tot, 1e-12f));
        }
    } else {
        // ---- bf16 convert: prompt then proj_w ----
        int i4 = (bid - (B_ + POOL_)) * 768 + t;      // 0 .. 1720319
        float4 v; unsigned short* d;
        if (i4 < (PROWS * C_ / 4)) {
            v = ((const float4*)prompt)[i4];
            d = Abf + (size_t)i4 * 4;
        } else {
            int j4 = i4 - PROWS * C_ / 4;
            v = ((const float4*)projw)[j4];
            d = Wbf + (size_t)j4 * 4;
        }
        ushort4 o; o.x = f2bf(v.x); o.y = f2bf(v.y); o.z = f2bf(v.z); o.w = f2bf(v.w);
        *(ushort4*)d = o;
    }
}

// ---------------- Kernel B: projection MFMA GEMM || similarity GEMM ---------
// 1024 blocks x 256 thr; K5-part (bid<768) and K3-part (bid>=768) co-resident
// (33.8 KB LDS total -> 4 blocks/CU covers the whole grid in one dispatch wave).
// K5: proj_all[8192,768] = Abf @ Wbf^T + bias + prompt ; 64x128 tile, BK=32,
//     2-phase double-buffered global_load_lds pipeline.
// K3: sim[256,1024] = (xmean @ pkey^T) * invx[m] * invp[n]  (factored norms;
//     row scaling is argmax-invariant, column scaling applied before store).
__global__ __launch_bounds__(256) void kB(const unsigned short* __restrict__ A,
                                          const unsigned short* __restrict__ W,
                                          const float* __restrict__ bias,
                                          const float* __restrict__ resid,
                                          float* __restrict__ projout,
                                          const float* __restrict__ xmean,
                                          const float* __restrict__ pkey,
                                          const float* __restrict__ invx,
                                          const float* __restrict__ invp,
                                          float* __restrict__ sim) {
    __shared__ short As5[2][64*32];
    __shared__ short Bs5[2][128*32];
    __shared__ float As3[32][36];
    __shared__ float Bs3[32][36];
    const int tid = threadIdx.x;
    const int bid = blockIdx.x;

    if (bid < 768) {
        // ================= K5: projection GEMM =================
        const int m0 = (bid / 6) * 64, n0 = (bid % 6) * 128;
        const int wave = tid >> 6, lane = tid & 63;
        const int quad = lane >> 4, lr = lane & 15;
        const int srow = tid >> 2;              // 0..63
        const int scol = (tid & 3) * 8;         // 0,8,16,24

        f32x4 acc[4][2] = {};

        auto stage = [&](int buf, int kt) {
            const int k0 = kt * 32;
            __builtin_amdgcn_global_load_lds(
                (const __attribute__((address_space(1))) void*)&A[(size_t)(m0 + srow) * C_ + k0 + scol],
                (__attribute__((address_space(3))) void*)&As5[buf][srow*32 + scol], 16, 0, 0);
            __builtin_amdgcn_global_load_lds(
                (const __attribute__((address_space(1))) void*)&W[(size_t)(n0 + srow) * C_ + k0 + scol],
                (__attribute__((address_space(3))) void*)&Bs5[buf][srow*32 + scol], 16, 0, 0);
            __builtin_amdgcn_global_load_lds(
                (const __attribute__((address_space(1))) void*)&W[(size_t)(n0 + 64 + srow) * C_ + k0 + scol],
                (__attribute__((address_space(3))) void*)&Bs5[buf][(64 + srow)*32 + scol], 16, 0, 0);
        };
        auto compute = [&](int buf) {
            short8_t af[4], bf[2];
            #pragma unroll
            for (int i = 0; i < 4; ++i)
                af[i] = *(const short8_t*)&As5[buf][(i*16 + lr)*32 + quad*8];
            #pragma unroll
            for (int j = 0; j < 2; ++j)
                bf[j] = *(const short8_t*)&Bs5[buf][(wave*32 + j*16 + lr)*32 + quad*8];
            #pragma unroll
            for (int i = 0; i < 4; ++i)
                #pragma unroll
                for (int j = 0; j < 2; ++j)
                    acc[i][j] = __builtin_amdgcn_mfma_f32_16x16x32_bf16(af[i], bf[j], acc[i][j], 0, 0, 0);
        };

        stage(0, 0);
        __syncthreads();
        int cur = 0;
        for (int kt = 0; kt < 23; ++kt) {
            stage(cur ^ 1, kt + 1);             // overlap next stage with compute
            compute(cur);
            __syncthreads();
            cur ^= 1;
        }
        compute(cur);

        #pragma unroll
        for (int j = 0; j < 2; ++j) {
            const int n = n0 + wave*32 + j*16 + lr;
            const float bn = bias[n];
            #pragma unroll
            for (int i = 0; i < 4; ++i) {
                const int mbase = m0 + i*16 + quad*4;
                #pragma unroll
                for (int r = 0; r < 4; ++r) {
                    const int m = mbase + r;
                    projout[(size_t)m * C_ + n] = acc[i][j][r] + bn + resid[(size_t)m * C_ + n];
                }
            }
        }
    } else {
        // ================= K3: similarity GEMM =================
        const int q = bid - 768;
        const int m0 = (q >> 5) * 32, n0 = (q & 31) * 32;
        const int t = tid;
        const int lrow = t >> 3, lc = (t & 7) * 4;
        const int ty = t >> 4, tx = t & 15;
        float a00 = 0.f, a01 = 0.f, a10 = 0.f, a11 = 0.f;
        float4 va = *(const float4*)&xmean[(size_t)(m0 + lrow) * C_ + lc];
        float4 vb = *(const float4*)&pkey [(size_t)(n0 + lrow) * C_ + lc];
        for (int k0 = 0; k0 < C_; k0 += 32) {
            __syncthreads();
            *(float4*)&As3[lrow][lc] = va;
            *(float4*)&Bs3[lrow][lc] = vb;
            __syncthreads();
            if (k0 + 32 < C_) {                 // prefetch next tile during compute
                va = *(const float4*)&xmean[(size_t)(m0 + lrow) * C_ + k0 + 32 + lc];
                vb = *(const float4*)&pkey [(size_t)(n0 + lrow) * C_ + k0 + 32 + lc];
            }
            #pragma unroll
            for (int kk = 0; kk < 32; kk += 4) {
                float4 A0 = *(const float4*)&As3[ty*2][kk];
                float4 A1 = *(const float4*)&As3[ty*2+1][kk];
                float4 B0 = *(const float4*)&Bs3[tx*2][kk];
                float4 B1 = *(const float4*)&Bs3[tx*2+1][kk];
                a00 += A0.x*B0.x; a00 += A0.y*B0.y; a00 += A0.z*B0.z; a00 += A0.w*B0.w;
                a01 += A0.x*B1.x; a01 += A0.y*B1.y; a01 += A0.z*B1.z; a01 += A0.w*B1.w;
                a10 += A1.x*B0.x; a10 += A1.y*B0.y; a10 += A1.z*B0.z; a10 += A1.w*B0.w;
                a11 += A1.x*B1.x; a11 += A1.y*B1.y; a11 += A1.z*B1.z; a11 += A1.w*B1.w;
            }
        }
        const float im0 = invx[m0 + ty*2], im1 = invx[m0 + ty*2 + 1];
        const float ip0 = invp[n0 + tx*2], ip1 = invp[n0 + tx*2 + 1];
        sim[(size_t)(m0 + ty*2    ) * POOL_ + n0 + tx*2    ] = a00 * im0 * ip0;
        sim[(size_t)(m0 + ty*2    ) * POOL_ + n0 + tx*2 + 1] = a01 * im0 * ip1;
        sim[(size_t)(m0 + ty*2 + 1) * POOL_ + n0 + tx*2    ] = a10 * im1 * ip0;
        sim[(size_t)(m0 + ty*2 + 1) * POOL_ + n0 + tx*2 + 1] = a11 * im1 * ip1;
    }
}

// ---------------- Kernel C: top-8 + gather + scalar (fused per block) -------
// One block per batch row: top-8 (lax.top_k tie semantics) with idx kept in
// LDS, then this block gathers its own 64 projected rows into out. The last
// block to finish (device-scope atomic counter) writes the reduce_sim scalar.
__global__ __launch_bounds__(256) void kC(const float* __restrict__ sim,
                                          const float* __restrict__ projall,
                                          float* __restrict__ accum,
                                          float* __restrict__ out) {
    __shared__ float vals[POOL_];
    __shared__ float wv[4];
    __shared__ int   wi[4];
    __shared__ int   sidx[TOPK_];
    const int b = blockIdx.x, t = threadIdx.x;
    const int wave = t >> 6, lane = t & 63;
    #pragma unroll
    for (int i = 0; i < 4; ++i) vals[t + 256*i] = sim[(size_t)b * POOL_ + t + 256*i];
    __syncthreads();
    float sumv = 0.0f;
    for (int k = 0; k < TOPK_; ++k) {
        float bv = -FLT_MAX; int bi = POOL_;
        #pragma unroll
        for (int i = 0; i < 4; ++i) {          // ascending n -> ties keep lower idx
            int n = t + 256*i;
            float v = vals[n];
            if (v > bv) { bv = v; bi = n; }
        }
        #pragma unroll
        for (int off = 32; off > 0; off >>= 1) {
            float v2 = __shfl_down(bv, off);
            int   i2 = __shfl_down(bi, off);
            if (v2 > bv || (v2 == bv && i2 < bi)) { bv = v2; bi = i2; }
        }
        if (lane == 0) { wv[wave] = bv; wi[wave] = bi; }
        __syncthreads();
        if (t == 0) {
            float fv = wv[0]; int fi = wi[0];
            #pragma unroll
            for (int w = 1; w < 4; ++w) {
                float v2 = wv[w]; int i2 = wi[w];
                if (v2 > fv || (v2 == fv && i2 < fi)) { fv = v2; fi = i2; }
            }
            sidx[k] = fi;
            sumv += fv;
            vals[fi] = -FLT_MAX;
        }
        __syncthreads();                       // also publishes sidx[k]
    }
    // ---- gather this row's 64 projected rows (wave w owns rows w*16..+15) --
    #pragma unroll 4
    for (int jj = 0; jj < 16; ++jj) {
        const int j = wave * 16 + jj;
        const int p = sidx[j >> 3];
        const int l = j & 7;
        const f32x4* src = (const f32x4*)projall + (size_t)(p * LEN_ + l) * 192;
        f32x4* dst = (f32x4*)out + (size_t)(b * OUTROWS + 1 + j) * 192;
        __builtin_nontemporal_store(src[lane],       &dst[lane]);
        __builtin_nontemporal_store(src[lane + 64],  &dst[lane + 64]);
        __builtin_nontemporal_store(src[lane + 128], &dst[lane + 128]);
    }
    // ---- reduce_sim scalar: last block writes it ----
    if (t == 0) {
        atomicAdd(&accum[0], sumv);
        __threadfence();                       // publish before counter bump
        int done = atomicAdd((int*)accum + 1, 1);
        if (done == B_ - 1) {
            float tot = atomicAdd(&accum[0], 0.0f);   // coherent read of total
            out[(size_t)B_ * OUTROWS * C_] = tot * (1.0f / (float)B_);
        }
    }
}

// ---------------- launcher ---------------------------------------------------
extern "C" void kernel_launch(void* const* d_in, const int* in_sizes, int n_in,
                              void* d_out, int out_size, void* d_ws, size_t ws_size,
                              hipStream_t stream) {
    const float* x_embed = (const float*)d_in[0];
    const float* prompt  = (const float*)d_in[1];
    const float* pkey    = (const float*)d_in[2];
    const float* projw   = (const float*)d_in[3];
    const float* projb   = (const float*)d_in[4];
    float* out = (float*)d_out;
    char* ws = (char*)d_ws;

    float*          xmean   = (float*)(ws + OFF_XMEAN);
    float*          invx    = (float*)(ws + OFF_INVX);
    float*          invp    = (float*)(ws + OFF_INVP);
    float*          sim     = (float*)(ws + OFF_SIM);
    float*          acc     = (float*)(ws + OFF_ACC);
    unsigned short* Abf     = (unsigned short*)(ws + OFF_ABF);
    unsigned short* Wbf     = (unsigned short*)(ws + OFF_WBF);
    float*          projall = (float*)(ws + OFF_PROJ);

    const int convBlocks = (PROWS * C_ / 4 + 768 * 768 / 4) / 768;   // 2240
    kA<<<B_ + POOL_ + convBlocks, 768, 0, stream>>>(x_embed, pkey, prompt, projw,
                                                    out, xmean, invx, invp, Abf, Wbf, acc);
    kB<<<1024, 256, 0, stream>>>(Abf, Wbf, projb, prompt, projall,
                                 xmean, pkey, invx, invp, sim);
    kC<<<B_, 256, 0, stream>>>(sim, projall, acc, out);
}

// Round 3
// 421.920 us; speedup vs baseline: 1.0045x; 1.0045x over previous
//
#include <hip/hip_runtime.h>
#include <float.h>
#include <math.h>

// Problem constants
#define B_    256
#define N_    197
#define C_    768
#define POOL_ 1024
#define LEN_  8
#define TOPK_ 8
#define PROWS (POOL_*LEN_)          // 8192 projected pool rows
#define OUTROWS 261                 // 1 + 64 + 196

typedef __attribute__((ext_vector_type(8))) short short8_t;
typedef __attribute__((ext_vector_type(4))) float f32x4;

// ---------------- workspace layout (byte offsets, 256-aligned) --------------
static const size_t OFF_XMEAN = 0;          //  256*768*4  =   786432
static const size_t OFF_SIM   = 786432;     // 256*1024*4  =  1048576
static const size_t OFF_ACC   = 1835008;    // [0]=sim sum (f32), [1]=block counter (i32)
static const size_t OFF_ABF   = 1835264;    // 8192*768*2  = 12582912
static const size_t OFF_WBF   = 14418176;   //  768*768*2  =  1179648
static const size_t OFF_PROJ  = 15597824;   // 8192*768*4  = 25165824 -> ends 40763648
// total ~40.8 MB

__device__ __forceinline__ unsigned short f2bf(float f) {
    unsigned int u = __float_as_uint(f);
    u += 0x7fffu + ((u >> 16) & 1u);              // round-to-nearest-even
    return (unsigned short)(u >> 16);
}

// ---------------- Kernel A: mean+copy (round-1-exact) | bf16 convert --------
// All 256-thread blocks:
//   bid [0,768):       fused mean-pool + concat copy (3 blocks per batch row,
//                      4 waves each; round-1 k1 code byte-for-byte)
//   bid [768,7488):    fp32 -> bf16 convert of prompt + proj_w
__global__ __launch_bounds__(256) void kA(const float* __restrict__ x,
                                          const float* __restrict__ prompt,
                                          const float* __restrict__ projw,
                                          float* __restrict__ out,
                                          float* __restrict__ xmean,
                                          unsigned short* __restrict__ Abf,
                                          unsigned short* __restrict__ Wbf,
                                          float* __restrict__ accum) {
    const int bid = blockIdx.x, t = threadIdx.x;
    if (bid == 0 && t == 0) { accum[0] = 0.0f; ((int*)accum)[1] = 0; }  // ws is poisoned
    if (bid < B_ * 3) {
        // ---- mean + copy ----
        __shared__ f32x4 red[4][64];
        const int b = bid / 3, seg = bid % 3;
        const int r = t >> 6;                   // wave id 0..3 = row phase
        const int c = t & 63;
        const int c4 = seg * 64 + c;            // float4 column 0..191
        const f32x4* xin  = (const f32x4*)x   + (size_t)b * (N_ * 192) + c4;
        f32x4*       outb = (f32x4*)out       + (size_t)b * (OUTROWS * 192) + c4;
        float sx = 0.f, sy = 0.f, sz = 0.f, sw = 0.f;
        #pragma unroll 7
        for (int n = r; n < 196; n += 4) {
            f32x4 v = __builtin_nontemporal_load(&xin[(size_t)n * 192]);
            sx += v.x; sy += v.y; sz += v.z; sw += v.w;
            int orow = (n == 0) ? 0 : (64 + n);
            __builtin_nontemporal_store(v, &outb[(size_t)orow * 192]);
        }
        if (r == 0) {                           // row 196 remainder
            f32x4 v = __builtin_nontemporal_load(&xin[(size_t)196 * 192]);
            sx += v.x; sy += v.y; sz += v.z; sw += v.w;
            __builtin_nontemporal_store(v, &outb[(size_t)260 * 192]);
        }
        f32x4 s; s.x = sx; s.y = sy; s.z = sz; s.w = sw;
        red[r][c] = s;
        __syncthreads();
        if (r == 0) {
            f32x4 a = red[0][c], b2 = red[1][c], c2 = red[2][c], d = red[3][c];
            const float inv = 1.0f / (float)N_;
            f32x4 m;
            m.x = (a.x + b2.x + c2.x + d.x) * inv;
            m.y = (a.y + b2.y + c2.y + d.y) * inv;
            m.z = (a.z + b2.z + c2.z + d.z) * inv;
            m.w = (a.w + b2.w + c2.w + d.w) * inv;
            ((f32x4*)xmean)[b * 192 + c4] = m;
        }
    } else {
        // ---- bf16 convert: prompt then proj_w ----
        int i4 = (bid - B_ * 3) * 256 + t;      // 0 .. 1720319
        float4 v; unsigned short* d;
        if (i4 < (PROWS * C_ / 4)) {
            v = ((const float4*)prompt)[i4];
            d = Abf + (size_t)i4 * 4;
        } else {
            int j4 = i4 - PROWS * C_ / 4;
            v = ((const float4*)projw)[j4];
            d = Wbf + (size_t)j4 * 4;
        }
        ushort4 o; o.x = f2bf(v.x); o.y = f2bf(v.y); o.z = f2bf(v.z); o.w = f2bf(v.w);
        *(ushort4*)d = o;
    }
}

// ---------------- Kernel B: projection MFMA GEMM || similarity GEMM ---------
// 1024 blocks x 256 thr, LDS manually OVERLAID in one 24 KB region (GEMM path
// uses all 24 KB; sim path 11.5 KB) -> same LDS/block as the round-1 GEMM.
// K5 (bid<768): proj_all = Abf @ Wbf^T + bias + prompt; 64x128 tile, BK=32,
//               2-phase double-buffered global_load_lds pipeline.
// K3 (bid>=768): sim = (xmean @ pkey^T) * invx[m] * invp[n]. Row norms are
//               computed IN-KERNEL from the very elements staged into LDS
//               (each element passes the store point exactly once) -- zero
//               extra global traffic, no invx/invp producers needed.
__global__ __launch_bounds__(256) void kB(const unsigned short* __restrict__ A,
                                          const unsigned short* __restrict__ W,
                                          const float* __restrict__ bias,
                                          const float* __restrict__ resid,
                                          float* __restrict__ projout,
                                          const float* __restrict__ xmean,
                                          const float* __restrict__ pkey,
                                          float* __restrict__ sim) {
    __shared__ __align__(16) char smem[24576];
    const int tid = threadIdx.x;
    const int bid = blockIdx.x;

    if (bid < 768) {
        // ================= projection GEMM =================
        short (*As5)[64*32]  = (short (*)[64*32])(smem);          //  8 KB
        short (*Bs5)[128*32] = (short (*)[128*32])(smem + 8192);  // 16 KB
        const int m0 = (bid / 6) * 64, n0 = (bid % 6) * 128;
        const int wave = tid >> 6, lane = tid & 63;
        const int quad = lane >> 4, lr = lane & 15;
        const int srow = tid >> 2;              // 0..63
        const int scol = (tid & 3) * 8;         // 0,8,16,24

        f32x4 acc[4][2] = {};

        auto stage = [&](int buf, int kt) {
            const int k0 = kt * 32;
            __builtin_amdgcn_global_load_lds(
                (const __attribute__((address_space(1))) void*)&A[(size_t)(m0 + srow) * C_ + k0 + scol],
                (__attribute__((address_space(3))) void*)&As5[buf][srow*32 + scol], 16, 0, 0);
            __builtin_amdgcn_global_load_lds(
                (const __attribute__((address_space(1))) void*)&W[(size_t)(n0 + srow) * C_ + k0 + scol],
                (__attribute__((address_space(3))) void*)&Bs5[buf][srow*32 + scol], 16, 0, 0);
            __builtin_amdgcn_global_load_lds(
                (const __attribute__((address_space(1))) void*)&W[(size_t)(n0 + 64 + srow) * C_ + k0 + scol],
                (__attribute__((address_space(3))) void*)&Bs5[buf][(64 + srow)*32 + scol], 16, 0, 0);
        };
        auto compute = [&](int buf) {
            short8_t af[4], bf[2];
            #pragma unroll
            for (int i = 0; i < 4; ++i)
                af[i] = *(const short8_t*)&As5[buf][(i*16 + lr)*32 + quad*8];
            #pragma unroll
            for (int j = 0; j < 2; ++j)
                bf[j] = *(const short8_t*)&Bs5[buf][(wave*32 + j*16 + lr)*32 + quad*8];
            #pragma unroll
            for (int i = 0; i < 4; ++i)
                #pragma unroll
                for (int j = 0; j < 2; ++j)
                    acc[i][j] = __builtin_amdgcn_mfma_f32_16x16x32_bf16(af[i], bf[j], acc[i][j], 0, 0, 0);
        };

        stage(0, 0);
        __syncthreads();
        int cur = 0;
        for (int kt = 0; kt < 23; ++kt) {
            stage(cur ^ 1, kt + 1);             // overlap next stage with compute
            compute(cur);
            __syncthreads();
            cur ^= 1;
        }
        compute(cur);

        #pragma unroll
        for (int j = 0; j < 2; ++j) {
            const int n = n0 + wave*32 + j*16 + lr;
            const float bn = bias[n];
            #pragma unroll
            for (int i = 0; i < 4; ++i) {
                const int mbase = m0 + i*16 + quad*4;
                #pragma unroll
                for (int r = 0; r < 4; ++r) {
                    const int m = mbase + r;
                    projout[(size_t)m * C_ + n] = acc[i][j][r] + bn + resid[(size_t)m * C_ + n];
                }
            }
        }
    } else {
        // ================= similarity GEMM (with in-kernel norms) ==========
        float (*As3)[36] = (float (*)[36])(smem);                 // 4608 B
        float (*Bs3)[36] = (float (*)[36])(smem + 4608);          // 4608 B
        float* sqA  = (float*)(smem + 9216);                      // [32][8]
        float* sqB  = (float*)(smem + 10240);                     // [32][8]
        float* invs = (float*)(smem + 11264);                     // [64]
        const int q = bid - 768;
        const int m0 = (q >> 5) * 32, n0 = (q & 31) * 32;
        const int t = tid;
        const int lrow = t >> 3, lc = (t & 7) * 4;
        const int ty = t >> 4, tx = t & 15;
        float a00 = 0.f, a01 = 0.f, a10 = 0.f, a11 = 0.f;
        float sqa = 0.f, sqb = 0.f;
        float4 va = *(const float4*)&xmean[(size_t)(m0 + lrow) * C_ + lc];
        float4 vb = *(const float4*)&pkey [(size_t)(n0 + lrow) * C_ + lc];
        for (int k0 = 0; k0 < C_; k0 += 32) {
            __syncthreads();
            *(float4*)&As3[lrow][lc] = va;
            *(float4*)&Bs3[lrow][lc] = vb;
            sqa += va.x*va.x + va.y*va.y + va.z*va.z + va.w*va.w;
            sqb += vb.x*vb.x + vb.y*vb.y + vb.z*vb.z + vb.w*vb.w;
            __syncthreads();
            if (k0 + 32 < C_) {                 // prefetch next tile during compute
                va = *(const float4*)&xmean[(size_t)(m0 + lrow) * C_ + k0 + 32 + lc];
                vb = *(const float4*)&pkey [(size_t)(n0 + lrow) * C_ + k0 + 32 + lc];
            }
            #pragma unroll
            for (int kk = 0; kk < 32; kk += 4) {
                float4 A0 = *(const float4*)&As3[ty*2][kk];
                float4 A1 = *(const float4*)&As3[ty*2+1][kk];
                float4 B0 = *(const float4*)&Bs3[tx*2][kk];
                float4 B1 = *(const float4*)&Bs3[tx*2+1][kk];
                a00 += A0.x*B0.x; a00 += A0.y*B0.y; a00 += A0.z*B0.z; a00 += A0.w*B0.w;
                a01 += A0.x*B1.x; a01 += A0.y*B1.y; a01 += A0.z*B1.z; a01 += A0.w*B1.w;
                a10 += A1.x*B0.x; a10 += A1.y*B0.y; a10 += A1.z*B0.z; a10 += A1.w*B0.w;
                a11 += A1.x*B1.x; a11 += A1.y*B1.y; a11 += A1.z*B1.z; a11 += A1.w*B1.w;
            }
        }
        // per-row squared-sum reduction (8 partial sums per row)
        sqA[lrow*8 + (t & 7)] = sqa;
        sqB[lrow*8 + (t & 7)] = sqb;
        __syncthreads();
        if (t < 64) {
            const float* s = (t < 32) ? sqA : sqB;
            const int rr = t & 31;
            float tot = 0.f;
            #pragma unroll
            for (int j = 0; j < 8; ++j) tot += s[rr*8 + j];
            invs[t] = 1.0f / sqrtf(fmaxf(tot, 1e-12f));
        }
        __syncthreads();
        const float im0 = invs[ty*2], im1 = invs[ty*2 + 1];
        const float ip0 = invs[32 + tx*2], ip1 = invs[32 + tx*2 + 1];
        sim[(size_t)(m0 + ty*2    ) * POOL_ + n0 + tx*2    ] = a00 * im0 * ip0;
        sim[(size_t)(m0 + ty*2    ) * POOL_ + n0 + tx*2 + 1] = a01 * im0 * ip1;
        sim[(size_t)(m0 + ty*2 + 1) * POOL_ + n0 + tx*2    ] = a10 * im1 * ip0;
        sim[(size_t)(m0 + ty*2 + 1) * POOL_ + n0 + tx*2 + 1] = a11 * im1 * ip1;
    }
}

// ---------------- Kernel C: top-8 + gather + scalar (fused per block) -------
// One block per batch row: top-8 (lax.top_k tie semantics) with idx kept in
// LDS, then this block gathers its own 64 projected rows into out. The last
// block to finish (device-scope atomic counter) writes the reduce_sim scalar.
__global__ __launch_bounds__(256) void kC(const float* __restrict__ sim,
                                          const float* __restrict__ projall,
                                          float* __restrict__ accum,
                                          float* __restrict__ out) {
    __shared__ float vals[POOL_];
    __shared__ float wv[4];
    __shared__ int   wi[4];
    __shared__ int   sidx[TOPK_];
    const int b = blockIdx.x, t = threadIdx.x;
    const int wave = t >> 6, lane = t & 63;
    #pragma unroll
    for (int i = 0; i < 4; ++i) vals[t + 256*i] = sim[(size_t)b * POOL_ + t + 256*i];
    __syncthreads();
    float sumv = 0.0f;
    for (int k = 0; k < TOPK_; ++k) {
        float bv = -FLT_MAX; int bi = POOL_;
        #pragma unroll
        for (int i = 0; i < 4; ++i) {          // ascending n -> ties keep lower idx
            int n = t + 256*i;
            float v = vals[n];
            if (v > bv) { bv = v; bi = n; }
        }
        #pragma unroll
        for (int off = 32; off > 0; off >>= 1) {
            float v2 = __shfl_down(bv, off);
            int   i2 = __shfl_down(bi, off);
            if (v2 > bv || (v2 == bv && i2 < bi)) { bv = v2; bi = i2; }
        }
        if (lane == 0) { wv[wave] = bv; wi[wave] = bi; }
        __syncthreads();
        if (t == 0) {
            float fv = wv[0]; int fi = wi[0];
            #pragma unroll
            for (int w = 1; w < 4; ++w) {
                float v2 = wv[w]; int i2 = wi[w];
                if (v2 > fv || (v2 == fv && i2 < fi)) { fv = v2; fi = i2; }
            }
            sidx[k] = fi;
            sumv += fv;
            vals[fi] = -FLT_MAX;
        }
        __syncthreads();                       // also publishes sidx[k]
    }
    // ---- gather this row's 64 projected rows (wave w owns rows w*16..+15) --
    #pragma unroll 4
    for (int jj = 0; jj < 16; ++jj) {
        const int j = wave * 16 + jj;
        const int p = sidx[j >> 3];
        const int l = j & 7;
        const f32x4* src = (const f32x4*)projall + (size_t)(p * LEN_ + l) * 192;
        f32x4* dst = (f32x4*)out + (size_t)(b * OUTROWS + 1 + j) * 192;
        __builtin_nontemporal_store(src[lane],       &dst[lane]);
        __builtin_nontemporal_store(src[lane + 64],  &dst[lane + 64]);
        __builtin_nontemporal_store(src[lane + 128], &dst[lane + 128]);
    }
    // ---- reduce_sim scalar: last block writes it ----
    if (t == 0) {
        atomicAdd(&accum[0], sumv);
        __threadfence();                       // publish before counter bump
        int done = atomicAdd((int*)accum + 1, 1);
        if (done == B_ - 1) {
            float tot = atomicAdd(&accum[0], 0.0f);   // coherent read of total
            out[(size_t)B_ * OUTROWS * C_] = tot * (1.0f / (float)B_);
        }
    }
}

// ---------------- launcher ---------------------------------------------------
extern "C" void kernel_launch(void* const* d_in, const int* in_sizes, int n_in,
                              void* d_out, int out_size, void* d_ws, size_t ws_size,
                              hipStream_t stream) {
    const float* x_embed = (const float*)d_in[0];
    const float* prompt  = (const float*)d_in[1];
    const float* pkey    = (const float*)d_in[2];
    const float* projw   = (const float*)d_in[3];
    const float* projb   = (const float*)d_in[4];
    float* out = (float*)d_out;
    char* ws = (char*)d_ws;

    float*          xmean   = (float*)(ws + OFF_XMEAN);
    float*          sim     = (float*)(ws + OFF_SIM);
    float*          acc     = (float*)(ws + OFF_ACC);
    unsigned short* Abf     = (unsigned short*)(ws + OFF_ABF);
    unsigned short* Wbf     = (unsigned short*)(ws + OFF_WBF);
    float*          projall = (float*)(ws + OFF_PROJ);

    const int convBlocks = (PROWS * C_ / 4 + 768 * 768 / 4) / 256;   // 6720
    kA<<<B_ * 3 + convBlocks, 256, 0, stream>>>(x_embed, prompt, projw,
                                                out, xmean, Abf, Wbf, acc);
    kB<<<1024, 256, 0, stream>>>(Abf, Wbf, projb, prompt, projall,
                                 xmean, pkey, sim);
    kC<<<B_, 256, 0, stream>>>(sim, projall, acc, out);
}

// Round 4
// 413.750 us; speedup vs baseline: 1.0243x; 1.0197x over previous
//
#include <hip/hip_runtime.h>
#include <float.h>
#include <math.h>

// Problem constants
#define B_    256
#define N_    197
#define C_    768
#define POOL_ 1024
#define LEN_  8
#define TOPK_ 8
#define PROWS (POOL_*LEN_)          // 8192 projected pool rows
#define OUTROWS 261                 // 1 + 64 + 196

typedef __attribute__((ext_vector_type(8))) short short8_t;
typedef __attribute__((ext_vector_type(4))) float f32x4;

// ---------------- workspace layout (byte offsets, 256-aligned) --------------
static const size_t OFF_XMEAN = 0;          //  256*768*4  =   786432
static const size_t OFF_SIM   = 786432;     // 256*1024*4  =  1048576
static const size_t OFF_IDX   = 1835008;    // 256*8*4     =     8192
static const size_t OFF_ACC   = 1843200;    // [0]=sim sum (f32)
static const size_t OFF_ABF   = 1843456;    // 8192*768*2  = 12582912
static const size_t OFF_WBF   = 14426368;   //  768*768*2  =  1179648
static const size_t OFF_PROJ  = 15606016;   // 8192*768*4  = 25165824 -> ends 40771840
// total ~40.8 MB

__device__ __forceinline__ unsigned short f2bf(float f) {
    unsigned int u = __float_as_uint(f);
    u += 0x7fffu + ((u >> 16) & 1u);              // round-to-nearest-even
    return (unsigned short)(u >> 16);
}

// ---------------- Kernel A: mean+copy (round-1-exact) | bf16 convert --------
// All 256-thread blocks:
//   bid [0,768):       fused mean-pool + concat copy (3 blocks per batch row)
//   bid [768,7488):    fp32 -> bf16 convert of prompt + proj_w
__global__ __launch_bounds__(256) void kA(const float* __restrict__ x,
                                          const float* __restrict__ prompt,
                                          const float* __restrict__ projw,
                                          float* __restrict__ out,
                                          float* __restrict__ xmean,
                                          unsigned short* __restrict__ Abf,
                                          unsigned short* __restrict__ Wbf,
                                          float* __restrict__ accum) {
    const int bid = blockIdx.x, t = threadIdx.x;
    if (bid == 0 && t == 0) accum[0] = 0.0f;      // ws is poisoned each iter
    if (bid < B_ * 3) {
        // ---- mean + copy ----
        __shared__ f32x4 red[4][64];
        const int b = bid / 3, seg = bid % 3;
        const int r = t >> 6;                   // wave id 0..3 = row phase
        const int c = t & 63;
        const int c4 = seg * 64 + c;            // float4 column 0..191
        const f32x4* xin  = (const f32x4*)x   + (size_t)b * (N_ * 192) + c4;
        f32x4*       outb = (f32x4*)out       + (size_t)b * (OUTROWS * 192) + c4;
        float sx = 0.f, sy = 0.f, sz = 0.f, sw = 0.f;
        #pragma unroll 7
        for (int n = r; n < 196; n += 4) {
            f32x4 v = __builtin_nontemporal_load(&xin[(size_t)n * 192]);
            sx += v.x; sy += v.y; sz += v.z; sw += v.w;
            int orow = (n == 0) ? 0 : (64 + n);
            __builtin_nontemporal_store(v, &outb[(size_t)orow * 192]);
        }
        if (r == 0) {                           // row 196 remainder
            f32x4 v = __builtin_nontemporal_load(&xin[(size_t)196 * 192]);
            sx += v.x; sy += v.y; sz += v.z; sw += v.w;
            __builtin_nontemporal_store(v, &outb[(size_t)260 * 192]);
        }
        f32x4 s; s.x = sx; s.y = sy; s.z = sz; s.w = sw;
        red[r][c] = s;
        __syncthreads();
        if (r == 0) {
            f32x4 a = red[0][c], b2 = red[1][c], c2 = red[2][c], d = red[3][c];
            const float inv = 1.0f / (float)N_;
            f32x4 m;
            m.x = (a.x + b2.x + c2.x + d.x) * inv;
            m.y = (a.y + b2.y + c2.y + d.y) * inv;
            m.z = (a.z + b2.z + c2.z + d.z) * inv;
            m.w = (a.w + b2.w + c2.w + d.w) * inv;
            ((f32x4*)xmean)[b * 192 + c4] = m;
        }
    } else {
        // ---- bf16 convert: prompt then proj_w ----
        int i4 = (bid - B_ * 3) * 256 + t;      // 0 .. 1720319
        float4 v; unsigned short* d;
        if (i4 < (PROWS * C_ / 4)) {
            v = ((const float4*)prompt)[i4];
            d = Abf + (size_t)i4 * 4;
        } else {
            int j4 = i4 - PROWS * C_ / 4;
            v = ((const float4*)projw)[j4];
            d = Wbf + (size_t)j4 * 4;
        }
        ushort4 o; o.x = f2bf(v.x); o.y = f2bf(v.y); o.z = f2bf(v.z); o.w = f2bf(v.w);
        *(ushort4*)d = o;
    }
}

// ---------------- Kernel B: projection MFMA GEMM || similarity GEMM ---------
// 1024 blocks x 256 thr, LDS manually OVERLAID in one 24 KB region.
// GEMM (bid<768): proj_all = Abf @ Wbf^T + bias + prompt; 64x128 tile, BK=32,
//                 2-phase double-buffered global_load_lds pipeline.
// sim (bid>=768): sim = (xmean @ pkey^T) * invx[m] * invp[n]; row norms
//                 computed in-kernel from the staged elements (zero extra
//                 global traffic) -- factored-norm form, argmax-invariant.
__global__ __launch_bounds__(256) void kB(const unsigned short* __restrict__ A,
                                          const unsigned short* __restrict__ W,
                                          const float* __restrict__ bias,
                                          const float* __restrict__ resid,
                                          float* __restrict__ projout,
                                          const float* __restrict__ xmean,
                                          const float* __restrict__ pkey,
                                          float* __restrict__ sim) {
    __shared__ __align__(16) char smem[24576];
    const int tid = threadIdx.x;
    const int bid = blockIdx.x;

    if (bid < 768) {
        // ================= projection GEMM =================
        short (*As5)[64*32]  = (short (*)[64*32])(smem);          //  8 KB
        short (*Bs5)[128*32] = (short (*)[128*32])(smem + 8192);  // 16 KB
        const int m0 = (bid / 6) * 64, n0 = (bid % 6) * 128;
        const int wave = tid >> 6, lane = tid & 63;
        const int quad = lane >> 4, lr = lane & 15;
        const int srow = tid >> 2;              // 0..63
        const int scol = (tid & 3) * 8;         // 0,8,16,24

        f32x4 acc[4][2] = {};

        auto stage = [&](int buf, int kt) {
            const int k0 = kt * 32;
            __builtin_amdgcn_global_load_lds(
                (const __attribute__((address_space(1))) void*)&A[(size_t)(m0 + srow) * C_ + k0 + scol],
                (__attribute__((address_space(3))) void*)&As5[buf][srow*32 + scol], 16, 0, 0);
            __builtin_amdgcn_global_load_lds(
                (const __attribute__((address_space(1))) void*)&W[(size_t)(n0 + srow) * C_ + k0 + scol],
                (__attribute__((address_space(3))) void*)&Bs5[buf][srow*32 + scol], 16, 0, 0);
            __builtin_amdgcn_global_load_lds(
                (const __attribute__((address_space(1))) void*)&W[(size_t)(n0 + 64 + srow) * C_ + k0 + scol],
                (__attribute__((address_space(3))) void*)&Bs5[buf][(64 + srow)*32 + scol], 16, 0, 0);
        };
        auto compute = [&](int buf) {
            short8_t af[4], bf[2];
            #pragma unroll
            for (int i = 0; i < 4; ++i)
                af[i] = *(const short8_t*)&As5[buf][(i*16 + lr)*32 + quad*8];
            #pragma unroll
            for (int j = 0; j < 2; ++j)
                bf[j] = *(const short8_t*)&Bs5[buf][(wave*32 + j*16 + lr)*32 + quad*8];
            #pragma unroll
            for (int i = 0; i < 4; ++i)
                #pragma unroll
                for (int j = 0; j < 2; ++j)
                    acc[i][j] = __builtin_amdgcn_mfma_f32_16x16x32_bf16(af[i], bf[j], acc[i][j], 0, 0, 0);
        };

        stage(0, 0);
        __syncthreads();
        int cur = 0;
        for (int kt = 0; kt < 23; ++kt) {
            stage(cur ^ 1, kt + 1);             // overlap next stage with compute
            compute(cur);
            __syncthreads();
            cur ^= 1;
        }
        compute(cur);

        #pragma unroll
        for (int j = 0; j < 2; ++j) {
            const int n = n0 + wave*32 + j*16 + lr;
            const float bn = bias[n];
            #pragma unroll
            for (int i = 0; i < 4; ++i) {
                const int mbase = m0 + i*16 + quad*4;
                #pragma unroll
                for (int r = 0; r < 4; ++r) {
                    const int m = mbase + r;
                    projout[(size_t)m * C_ + n] = acc[i][j][r] + bn + resid[(size_t)m * C_ + n];
                }
            }
        }
    } else {
        // ================= similarity GEMM (with in-kernel norms) ==========
        float (*As3)[36] = (float (*)[36])(smem);                 // 4608 B
        float (*Bs3)[36] = (float (*)[36])(smem + 4608);          // 4608 B
        float* sqA  = (float*)(smem + 9216);                      // [32][8]
        float* sqB  = (float*)(smem + 10240);                     // [32][8]
        float* invs = (float*)(smem + 11264);                     // [64]
        const int q = bid - 768;
        const int m0 = (q >> 5) * 32, n0 = (q & 31) * 32;
        const int t = tid;
        const int lrow = t >> 3, lc = (t & 7) * 4;
        const int ty = t >> 4, tx = t & 15;
        float a00 = 0.f, a01 = 0.f, a10 = 0.f, a11 = 0.f;
        float sqa = 0.f, sqb = 0.f;
        float4 va = *(const float4*)&xmean[(size_t)(m0 + lrow) * C_ + lc];
        float4 vb = *(const float4*)&pkey [(size_t)(n0 + lrow) * C_ + lc];
        for (int k0 = 0; k0 < C_; k0 += 32) {
            __syncthreads();
            *(float4*)&As3[lrow][lc] = va;
            *(float4*)&Bs3[lrow][lc] = vb;
            sqa += va.x*va.x + va.y*va.y + va.z*va.z + va.w*va.w;
            sqb += vb.x*vb.x + vb.y*vb.y + vb.z*vb.z + vb.w*vb.w;
            __syncthreads();
            if (k0 + 32 < C_) {                 // prefetch next tile during compute
                va = *(const float4*)&xmean[(size_t)(m0 + lrow) * C_ + k0 + 32 + lc];
                vb = *(const float4*)&pkey [(size_t)(n0 + lrow) * C_ + k0 + 32 + lc];
            }
            #pragma unroll
            for (int kk = 0; kk < 32; kk += 4) {
                float4 A0 = *(const float4*)&As3[ty*2][kk];
                float4 A1 = *(const float4*)&As3[ty*2+1][kk];
                float4 B0 = *(const float4*)&Bs3[tx*2][kk];
                float4 B1 = *(const float4*)&Bs3[tx*2+1][kk];
                a00 += A0.x*B0.x; a00 += A0.y*B0.y; a00 += A0.z*B0.z; a00 += A0.w*B0.w;
                a01 += A0.x*B1.x; a01 += A0.y*B1.y; a01 += A0.z*B1.z; a01 += A0.w*B1.w;
                a10 += A1.x*B0.x; a10 += A1.y*B0.y; a10 += A1.z*B0.z; a10 += A1.w*B0.w;
                a11 += A1.x*B1.x; a11 += A1.y*B1.y; a11 += A1.z*B1.z; a11 += A1.w*B1.w;
            }
        }
        // per-row squared-sum reduction (8 partial sums per row)
        sqA[lrow*8 + (t & 7)] = sqa;
        sqB[lrow*8 + (t & 7)] = sqb;
        __syncthreads();
        if (t < 64) {
            const float* s = (t < 32) ? sqA : sqB;
            const int rr = t & 31;
            float tot = 0.f;
            #pragma unroll
            for (int j = 0; j < 8; ++j) tot += s[rr*8 + j];
            invs[t] = 1.0f / sqrtf(fmaxf(tot, 1e-12f));
        }
        __syncthreads();
        const float im0 = invs[ty*2], im1 = invs[ty*2 + 1];
        const float ip0 = invs[32 + tx*2], ip1 = invs[32 + tx*2 + 1];
        sim[(size_t)(m0 + ty*2    ) * POOL_ + n0 + tx*2    ] = a00 * im0 * ip0;
        sim[(size_t)(m0 + ty*2    ) * POOL_ + n0 + tx*2 + 1] = a01 * im0 * ip1;
        sim[(size_t)(m0 + ty*2 + 1) * POOL_ + n0 + tx*2    ] = a10 * im1 * ip0;
        sim[(size_t)(m0 + ty*2 + 1) * POOL_ + n0 + tx*2 + 1] = a11 * im1 * ip1;
    }
}

// ---------------- Kernel C1: top-8 per row (lax.top_k semantics) ------------
// One block per row; writes idx + atomicAdd of selected sim values.
__global__ __launch_bounds__(256) void kC1_topk(const float* __restrict__ sim,
                                                int* __restrict__ idx,
                                                float* __restrict__ accum) {
    __shared__ float vals[POOL_];
    __shared__ float wv[4];
    __shared__ int   wi[4];
    const int b = blockIdx.x, t = threadIdx.x;
    const int wave = t >> 6;
    #pragma unroll
    for (int i = 0; i < 4; ++i) vals[t + 256*i] = sim[(size_t)b * POOL_ + t + 256*i];
    __syncthreads();
    float sumv = 0.0f;
    for (int k = 0; k < TOPK_; ++k) {
        float bv = -FLT_MAX; int bi = POOL_;
        #pragma unroll
        for (int i = 0; i < 4; ++i) {          // ascending n -> ties keep lower idx
            int n = t + 256*i;
            float v = vals[n];
            if (v > bv) { bv = v; bi = n; }
        }
        #pragma unroll
        for (int off = 32; off > 0; off >>= 1) {
            float v2 = __shfl_down(bv, off);
            int   i2 = __shfl_down(bi, off);
            if (v2 > bv || (v2 == bv && i2 < bi)) { bv = v2; bi = i2; }
        }
        if ((t & 63) == 0) { wv[wave] = bv; wi[wave] = bi; }
        __syncthreads();
        if (t == 0) {
            float fv = wv[0]; int fi = wi[0];
            #pragma unroll
            for (int w = 1; w < 4; ++w) {
                float v2 = wv[w]; int i2 = wi[w];
                if (v2 > fv || (v2 == fv && i2 < fi)) { fv = v2; fi = i2; }
            }
            idx[b*TOPK_ + k] = fi;
            sumv += fv;
            vals[fi] = -FLT_MAX;
        }
        __syncthreads();
    }
    if (t == 0) atomicAdd(accum, sumv);
}

// ---------------- Kernel C2: gather projected rows into output + scalar -----
// 4096 blocks x 256 thr (4 rows each) -- full memory-level parallelism.
__global__ __launch_bounds__(256) void kC2_gather(const float* __restrict__ projall,
                                                  const int* __restrict__ idx,
                                                  const float* __restrict__ accum,
                                                  float* __restrict__ out) {
    int row = blockIdx.x * 4 + (threadIdx.x >> 6);   // 0..16383 = (b, j)
    int t = threadIdx.x & 63;
    int b = row >> 6, j = row & 63;
    int k = j >> 3, l = j & 7;
    int p = idx[b * TOPK_ + k];
    const f32x4* src = (const f32x4*)projall + (size_t)(p * LEN_ + l) * 192;
    f32x4* dst = (f32x4*)out + (size_t)(b * OUTROWS + 1 + j) * 192;
    __builtin_nontemporal_store(src[t],       &dst[t]);
    __builtin_nontemporal_store(src[t + 64],  &dst[t + 64]);
    __builtin_nontemporal_store(src[t + 128], &dst[t + 128]);
    if (row == 0 && t == 0)                    // accum complete (stream order)
        out[(size_t)B_ * OUTROWS * C_] = accum[0] * (1.0f / (float)B_);
}

// ---------------- launcher ---------------------------------------------------
extern "C" void kernel_launch(void* const* d_in, const int* in_sizes, int n_in,
                              void* d_out, int out_size, void* d_ws, size_t ws_size,
                              hipStream_t stream) {
    const float* x_embed = (const float*)d_in[0];
    const float* prompt  = (const float*)d_in[1];
    const float* pkey    = (const float*)d_in[2];
    const float* projw   = (const float*)d_in[3];
    const float* projb   = (const float*)d_in[4];
    float* out = (float*)d_out;
    char* ws = (char*)d_ws;

    float*          xmean   = (float*)(ws + OFF_XMEAN);
    float*          sim     = (float*)(ws + OFF_SIM);
    int*            idxp    = (int*)(ws + OFF_IDX);
    float*          acc     = (float*)(ws + OFF_ACC);
    unsigned short* Abf     = (unsigned short*)(ws + OFF_ABF);
    unsigned short* Wbf     = (unsigned short*)(ws + OFF_WBF);
    float*          projall = (float*)(ws + OFF_PROJ);

    const int convBlocks = (PROWS * C_ / 4 + 768 * 768 / 4) / 256;   // 6720
    kA<<<B_ * 3 + convBlocks, 256, 0, stream>>>(x_embed, prompt, projw,
                                                out, xmean, Abf, Wbf, acc);
    kB<<<1024, 256, 0, stream>>>(Abf, Wbf, projb, prompt, projall,
                                 xmean, pkey, sim);
    kC1_topk<<<B_, 256, 0, stream>>>(sim, idxp, acc);
    kC2_gather<<<B_ * 64 / 4, 256, 0, stream>>>(projall, idxp, acc, out);
}

// Round 5
// 410.962 us; speedup vs baseline: 1.0312x; 1.0068x over previous
//
#include <hip/hip_runtime.h>
#include <float.h>
#include <math.h>

// Problem constants
#define B_    256
#define N_    197
#define C_    768
#define POOL_ 1024
#define LEN_  8
#define TOPK_ 8
#define PROWS (POOL_*LEN_)          // 8192 projected pool rows
#define OUTROWS 261                 // 1 + 64 + 196

typedef __attribute__((ext_vector_type(8))) short short8_t;
typedef __attribute__((ext_vector_type(4))) float f32x4;

// ---------------- workspace layout (byte offsets, 256-aligned) --------------
static const size_t OFF_XMEAN = 0;          //  256*768*4  =   786432
static const size_t OFF_SIM   = 786432;     // 256*1024*4  =  1048576 -> 1835008
static const size_t OFF_ACC   = 1835008;    // [0]=sim sum (f32)         -> 1835264
static const size_t OFF_CNT   = 1835264;    // 1024*4                    -> 1839360
static const size_t OFF_ENT   = 1839360;    // 1024*256*4 = 1048576      -> 2887936
static const size_t OFF_ABF   = 2887936;    // 8192*768*2 = 12582912     -> 15470848
static const size_t OFF_WBF   = 15470848;   //  768*768*2 =  1179648     -> 16650496
// total ~16.7 MB

__device__ __forceinline__ unsigned short f2bf(float f) {
    unsigned int u = __float_as_uint(f);
    u += 0x7fffu + ((u >> 16) & 1u);              // round-to-nearest-even
    return (unsigned short)(u >> 16);
}

// ---------------- Kernel A: mean-pool | zero cnt/acc | bf16 convert ---------
//   bid [0,768):    mean only (3 blocks per batch row). REGULAR loads so x
//                   becomes L3-resident for S's copy re-read (155MB < 256MB L3).
//                   Mean arithmetic bit-identical to prior rounds.
//   bid == 768:     zero cnt[1024] + accum
//   bid (768,7489): fp32 -> bf16 convert of prompt + proj_w
__global__ __launch_bounds__(256) void kA(const float* __restrict__ x,
                                          const float* __restrict__ prompt,
                                          const float* __restrict__ projw,
                                          float* __restrict__ xmean,
                                          unsigned short* __restrict__ Abf,
                                          unsigned short* __restrict__ Wbf,
                                          int* __restrict__ cnt,
                                          float* __restrict__ accum) {
    const int bid = blockIdx.x, t = threadIdx.x;
    if (bid < B_ * 3) {
        // ---- mean (same accumulation order as prior rounds) ----
        __shared__ f32x4 red[4][64];
        const int b = bid / 3, seg = bid % 3;
        const int r = t >> 6;                   // wave id 0..3 = row phase
        const int c = t & 63;
        const int c4 = seg * 64 + c;            // float4 column 0..191
        const f32x4* xin = (const f32x4*)x + (size_t)b * (N_ * 192) + c4;
        float sx = 0.f, sy = 0.f, sz = 0.f, sw = 0.f;
        #pragma unroll 7
        for (int n = r; n < 196; n += 4) {
            f32x4 v = xin[(size_t)n * 192];
            sx += v.x; sy += v.y; sz += v.z; sw += v.w;
        }
        if (r == 0) {                           // row 196 remainder
            f32x4 v = xin[(size_t)196 * 192];
            sx += v.x; sy += v.y; sz += v.z; sw += v.w;
        }
        f32x4 s; s.x = sx; s.y = sy; s.z = sz; s.w = sw;
        red[r][c] = s;
        __syncthreads();
        if (r == 0) {
            f32x4 a = red[0][c], b2 = red[1][c], c2 = red[2][c], d = red[3][c];
            const float inv = 1.0f / (float)N_;
            f32x4 m;
            m.x = (a.x + b2.x + c2.x + d.x) * inv;
            m.y = (a.y + b2.y + c2.y + d.y) * inv;
            m.z = (a.z + b2.z + c2.z + d.z) * inv;
            m.w = (a.w + b2.w + c2.w + d.w) * inv;
            ((f32x4*)xmean)[b * 192 + c4] = m;
        }
    } else if (bid == B_ * 3) {
        // ---- zero CSR counters + accumulator (ws is poisoned each iter) ----
        ((f32x4*)cnt)[t] = f32x4{0.f, 0.f, 0.f, 0.f};   // 256*16B = 4KB
        if (t == 0) accum[0] = 0.0f;
    } else {
        // ---- bf16 convert: prompt then proj_w ----
        int i4 = (bid - (B_ * 3 + 1)) * 256 + t;  // 0 .. 1720319
        float4 v; unsigned short* d;
        if (i4 < (PROWS * C_ / 4)) {
            v = ((const float4*)prompt)[i4];
            d = Abf + (size_t)i4 * 4;
        } else {
            int j4 = i4 - PROWS * C_ / 4;
            v = ((const float4*)projw)[j4];
            d = Wbf + (size_t)j4 * 4;
        }
        ushort4 o; o.x = f2bf(v.x); o.y = f2bf(v.y); o.z = f2bf(v.z); o.w = f2bf(v.w);
        *(ushort4*)d = o;
    }
}

// ---------------- Kernel S: similarity GEMM || x->out concat copy -----------
//   bid [0,256):    sim = (xmean @ pkey^T) * invx[m] * invp[n], norms computed
//                   in-kernel from staged elements (proven R3/R4; bit-identical)
//   bid [256,1024): copy x rows into out (x re-read from L3, NT stores to HBM)
//                   -- the 155MB copy-write streams while sim computes.
__global__ __launch_bounds__(256) void kS(const float* __restrict__ xmean,
                                          const float* __restrict__ pkey,
                                          float* __restrict__ sim,
                                          const float* __restrict__ x,
                                          float* __restrict__ out) {
    __shared__ float As3[32][36];
    __shared__ float Bs3[32][36];
    __shared__ float sqA[32*8];
    __shared__ float sqB[32*8];
    __shared__ float invs[64];
    const int bid = blockIdx.x, t = threadIdx.x;

    if (bid < 256) {
        // ================= similarity GEMM (with in-kernel norms) ==========
        const int m0 = (bid >> 5) * 32, n0 = (bid & 31) * 32;
        const int lrow = t >> 3, lc = (t & 7) * 4;
        const int ty = t >> 4, tx = t & 15;
        float a00 = 0.f, a01 = 0.f, a10 = 0.f, a11 = 0.f;
        float sqa = 0.f, sqb = 0.f;
        float4 va = *(const float4*)&xmean[(size_t)(m0 + lrow) * C_ + lc];
        float4 vb = *(const float4*)&pkey [(size_t)(n0 + lrow) * C_ + lc];
        for (int k0 = 0; k0 < C_; k0 += 32) {
            __syncthreads();
            *(float4*)&As3[lrow][lc] = va;
            *(float4*)&Bs3[lrow][lc] = vb;
            sqa += va.x*va.x + va.y*va.y + va.z*va.z + va.w*va.w;
            sqb += vb.x*vb.x + vb.y*vb.y + vb.z*vb.z + vb.w*vb.w;
            __syncthreads();
            if (k0 + 32 < C_) {                 // prefetch next tile
                va = *(const float4*)&xmean[(size_t)(m0 + lrow) * C_ + k0 + 32 + lc];
                vb = *(const float4*)&pkey [(size_t)(n0 + lrow) * C_ + k0 + 32 + lc];
            }
            #pragma unroll
            for (int kk = 0; kk < 32; kk += 4) {
                float4 A0 = *(const float4*)&As3[ty*2][kk];
                float4 A1 = *(const float4*)&As3[ty*2+1][kk];
                float4 B0 = *(const float4*)&Bs3[tx*2][kk];
                float4 B1 = *(const float4*)&Bs3[tx*2+1][kk];
                a00 += A0.x*B0.x; a00 += A0.y*B0.y; a00 += A0.z*B0.z; a00 += A0.w*B0.w;
                a01 += A0.x*B1.x; a01 += A0.y*B1.y; a01 += A0.z*B1.z; a01 += A0.w*B1.w;
                a10 += A1.x*B0.x; a10 += A1.y*B0.y; a10 += A1.z*B0.z; a10 += A1.w*B0.w;
                a11 += A1.x*B1.x; a11 += A1.y*B1.y; a11 += A1.z*B1.z; a11 += A1.w*B1.w;
            }
        }
        sqA[lrow*8 + (t & 7)] = sqa;
        sqB[lrow*8 + (t & 7)] = sqb;
        __syncthreads();
        if (t < 64) {
            const float* s = (t < 32) ? sqA : sqB;
            const int rr = t & 31;
            float tot = 0.f;
            #pragma unroll
            for (int j = 0; j < 8; ++j) tot += s[rr*8 + j];
            invs[t] = 1.0f / sqrtf(fmaxf(tot, 1e-12f));
        }
        __syncthreads();
        const float im0 = invs[ty*2], im1 = invs[ty*2 + 1];
        const float ip0 = invs[32 + tx*2], ip1 = invs[32 + tx*2 + 1];
        sim[(size_t)(m0 + ty*2    ) * POOL_ + n0 + tx*2    ] = a00 * im0 * ip0;
        sim[(size_t)(m0 + ty*2    ) * POOL_ + n0 + tx*2 + 1] = a01 * im0 * ip1;
        sim[(size_t)(m0 + ty*2 + 1) * POOL_ + n0 + tx*2    ] = a10 * im1 * ip0;
        sim[(size_t)(m0 + ty*2 + 1) * POOL_ + n0 + tx*2 + 1] = a11 * im1 * ip1;
    } else {
        // ================= concat copy =================
        const int cb = bid - 256;
        const int b = cb / 3, seg = cb % 3;
        const int r = t >> 6, c = t & 63;
        const int c4 = seg * 64 + c;
        const f32x4* xin  = (const f32x4*)x   + (size_t)b * (N_ * 192) + c4;
        f32x4*       outb = (f32x4*)out       + (size_t)b * (OUTROWS * 192) + c4;
        #pragma unroll 7
        for (int n = r; n < 196; n += 4) {
            f32x4 v = xin[(size_t)n * 192];     // L3 hit (A read x)
            int orow = (n == 0) ? 0 : (64 + n);
            __builtin_nontemporal_store(v, &outb[(size_t)orow * 192]);
        }
        if (r == 0) {
            f32x4 v = xin[(size_t)196 * 192];
            __builtin_nontemporal_store(v, &outb[(size_t)260 * 192]);
        }
    }
}

// ---------------- Kernel T: top-8 per row + inverted CSR index --------------
// One block per row; lax.top_k tie semantics (proven). After selection,
// 8 threads append (b,k) to the per-pool-entry CSR via device-scope atomics.
__global__ __launch_bounds__(256) void kT(const float* __restrict__ sim,
                                          int* __restrict__ cnt,
                                          int* __restrict__ entries,
                                          float* __restrict__ accum) {
    __shared__ float vals[POOL_];
    __shared__ float wv[4];
    __shared__ int   wi[4];
    __shared__ int   sidx[TOPK_];
    const int b = blockIdx.x, t = threadIdx.x;
    const int wave = t >> 6;
    #pragma unroll
    for (int i = 0; i < 4; ++i) vals[t + 256*i] = sim[(size_t)b * POOL_ + t + 256*i];
    __syncthreads();
    float sumv = 0.0f;
    for (int k = 0; k < TOPK_; ++k) {
        float bv = -FLT_MAX; int bi = POOL_;
        #pragma unroll
        for (int i = 0; i < 4; ++i) {          // ascending n -> ties keep lower idx
            int n = t + 256*i;
            float v = vals[n];
            if (v > bv) { bv = v; bi = n; }
        }
        #pragma unroll
        for (int off = 32; off > 0; off >>= 1) {
            float v2 = __shfl_down(bv, off);
            int   i2 = __shfl_down(bi, off);
            if (v2 > bv || (v2 == bv && i2 < bi)) { bv = v2; bi = i2; }
        }
        if ((t & 63) == 0) { wv[wave] = bv; wi[wave] = bi; }
        __syncthreads();
        if (t == 0) {
            float fv = wv[0]; int fi = wi[0];
            #pragma unroll
            for (int w = 1; w < 4; ++w) {
                float v2 = wv[w]; int i2 = wi[w];
                if (v2 > fv || (v2 == fv && i2 < fi)) { fv = v2; fi = i2; }
            }
            sidx[k] = fi;
            sumv += fv;
            vals[fi] = -FLT_MAX;
        }
        __syncthreads();                       // publishes sidx[k]
    }
    if (t < TOPK_) {                           // CSR append (order irrelevant)
        const int p = sidx[t];
        const int pos = atomicAdd(&cnt[p], 1);
        entries[(p << 8) + pos] = (b << 3) | t;
    }
    if (t == 0) atomicAdd(accum, sumv);
}

// ---------------- Kernel G: projection GEMM + scatter epilogue + scalar -----
// For all 8192 pool rows: val = Abf @ Wbf^T + bias + prompt. Instead of
// materializing projall, each value is scattered directly to every out row
// that selected its pool entry (CSR from kT). Unselected rows write nothing.
__global__ __launch_bounds__(256) void kG(const unsigned short* __restrict__ A,
                                          const unsigned short* __restrict__ W,
                                          const float* __restrict__ bias,
                                          const float* __restrict__ resid,
                                          const int* __restrict__ cnt,
                                          const int* __restrict__ entries,
                                          const float* __restrict__ accum,
                                          float* __restrict__ out) {
    __shared__ short As5[2][64*32];
    __shared__ short Bs5[2][128*32];
    const int tid = threadIdx.x;
    const int bid = blockIdx.x;
    if (bid == 0 && tid == 0)                  // accum complete (stream order)
        out[(size_t)B_ * OUTROWS * C_] = accum[0] * (1.0f / (float)B_);

    const int m0 = (bid / 6) * 64, n0 = (bid % 6) * 128;
    const int wave = tid >> 6, lane = tid & 63;
    const int quad = lane >> 4, lr = lane & 15;
    const int srow = tid >> 2;                  // 0..63
    const int scol = (tid & 3) * 8;             // 0,8,16,24

    f32x4 acc[4][2] = {};

    auto stage = [&](int buf, int kt) {
        const int k0 = kt * 32;
        __builtin_amdgcn_global_load_lds(
            (const __attribute__((address_space(1))) void*)&A[(size_t)(m0 + srow) * C_ + k0 + scol],
            (__attribute__((address_space(3))) void*)&As5[buf][srow*32 + scol], 16, 0, 0);
        __builtin_amdgcn_global_load_lds(
            (const __attribute__((address_space(1))) void*)&W[(size_t)(n0 + srow) * C_ + k0 + scol],
            (__attribute__((address_space(3))) void*)&Bs5[buf][srow*32 + scol], 16, 0, 0);
        __builtin_amdgcn_global_load_lds(
            (const __attribute__((address_space(1))) void*)&W[(size_t)(n0 + 64 + srow) * C_ + k0 + scol],
            (__attribute__((address_space(3))) void*)&Bs5[buf][(64 + srow)*32 + scol], 16, 0, 0);
    };
    auto compute = [&](int buf) {
        short8_t af[4], bf[2];
        #pragma unroll
        for (int i = 0; i < 4; ++i)
            af[i] = *(const short8_t*)&As5[buf][(i*16 + lr)*32 + quad*8];
        #pragma unroll
        for (int j = 0; j < 2; ++j)
            bf[j] = *(const short8_t*)&Bs5[buf][(wave*32 + j*16 + lr)*32 + quad*8];
        #pragma unroll
        for (int i = 0; i < 4; ++i)
            #pragma unroll
            for (int j = 0; j < 2; ++j)
                acc[i][j] = __builtin_amdgcn_mfma_f32_16x16x32_bf16(af[i], bf[j], acc[i][j], 0, 0, 0);
    };

    stage(0, 0);
    __syncthreads();
    int cur = 0;
    for (int kt = 0; kt < 23; ++kt) {
        stage(cur ^ 1, kt + 1);                 // overlap next stage with compute
        compute(cur);
        __syncthreads();
        cur ^= 1;
    }
    compute(cur);

    // ---- scatter epilogue ----
    const float bn0 = bias[n0 + wave*32 + lr];
    const float bn1 = bias[n0 + wave*32 + 16 + lr];
    const int ncol = n0 + wave*32 + lr;         // j stride = 16
    #pragma unroll
    for (int i = 0; i < 4; ++i) {
        const int m  = m0 + i*16 + quad*4;      // rows m..m+3
        const int p  = m >> 3;                  // pool entry (uniform over r)
        const int lb = m & 7;                   // prompt-slot for r=0 (r adds)
        const int c  = cnt[p];
        if (c != 0) {
            float vals[2][4];
            #pragma unroll
            for (int r = 0; r < 4; ++r) {
                vals[0][r] = acc[i][0][r] + bn0 + resid[(size_t)(m + r) * C_ + ncol];
                vals[1][r] = acc[i][1][r] + bn1 + resid[(size_t)(m + r) * C_ + ncol + 16];
            }
            for (int h = 0; h < c; ++h) {
                const int bk = entries[(p << 8) + h];
                const size_t obase =
                    (size_t)((bk >> 3) * OUTROWS + 1 + (bk & 7) * 8 + lb) * C_ + ncol;
                #pragma unroll
                for (int r = 0; r < 4; ++r) {
                    out[obase + (size_t)r * C_]      = vals[0][r];
                    out[obase + (size_t)r * C_ + 16] = vals[1][r];
                }
            }
        }
    }
}

// ---------------- launcher ---------------------------------------------------
extern "C" void kernel_launch(void* const* d_in, const int* in_sizes, int n_in,
                              void* d_out, int out_size, void* d_ws, size_t ws_size,
                              hipStream_t stream) {
    const float* x_embed = (const float*)d_in[0];
    const float* prompt  = (const float*)d_in[1];
    const float* pkey    = (const float*)d_in[2];
    const float* projw   = (const float*)d_in[3];
    const float* projb   = (const float*)d_in[4];
    float* out = (float*)d_out;
    char* ws = (char*)d_ws;

    float*          xmean   = (float*)(ws + OFF_XMEAN);
    float*          sim     = (float*)(ws + OFF_SIM);
    float*          acc     = (float*)(ws + OFF_ACC);
    int*            cnt     = (int*)(ws + OFF_CNT);
    int*            ent     = (int*)(ws + OFF_ENT);
    unsigned short* Abf     = (unsigned short*)(ws + OFF_ABF);
    unsigned short* Wbf     = (unsigned short*)(ws + OFF_WBF);

    const int convBlocks = (PROWS * C_ / 4 + 768 * 768 / 4) / 256;   // 6720
    kA<<<B_ * 3 + 1 + convBlocks, 256, 0, stream>>>(x_embed, prompt, projw,
                                                    xmean, Abf, Wbf, cnt, acc);
    kS<<<1024, 256, 0, stream>>>(xmean, pkey, sim, x_embed, out);
    kT<<<B_, 256, 0, stream>>>(sim, cnt, ent, acc);
    kG<<<768, 256, 0, stream>>>(Abf, Wbf, projb, prompt, cnt, ent, acc, out);
}

// Round 6
// 399.304 us; speedup vs baseline: 1.0613x; 1.0292x over previous
//
#include <hip/hip_runtime.h>
#include <float.h>
#include <math.h>

// Problem constants
#define B_    256
#define N_    197
#define C_    768
#define POOL_ 1024
#define LEN_  8
#define TOPK_ 8
#define PROWS (POOL_*LEN_)          // 8192 projected pool rows
#define OUTROWS 261                 // 1 + 64 + 196

typedef __attribute__((ext_vector_type(8))) short short8_t;
typedef __attribute__((ext_vector_type(4))) float f32x4;

// ---------------- workspace layout (byte offsets, 256-aligned) --------------
static const size_t OFF_XMEAN = 0;          //  256*768*4  =   786432
static const size_t OFF_SIM   = 786432;     // 256*1024*4  =  1048576 -> 1835008
static const size_t OFF_ACC   = 1835008;    // [0]=sim sum (f32)         -> 1835264
static const size_t OFF_CNT   = 1835264;    // 1024*4                    -> 1839360
static const size_t OFF_ENT   = 1839360;    // 1024*256*4 = 1048576      -> 2887936
static const size_t OFF_ABF   = 2887936;    // 8192*768*2 = 12582912     -> 15470848
static const size_t OFF_WBF   = 15470848;   //  768*768*2 =  1179648     -> 16650496
// total ~16.7 MB

__device__ __forceinline__ unsigned short f2bf(float f) {
    unsigned int u = __float_as_uint(f);
    u += 0x7fffu + ((u >> 16) & 1u);              // round-to-nearest-even
    return (unsigned short)(u >> 16);
}

// ---------------- Kernel A: mean+copy (R1-exact single pass) | zero | convert
//   bid [0,768):    fused mean-pool + concat copy (3 blocks per batch row,
//                   4 waves each; ONE x read, NT loads + NT out stores)
//   bid == 768:     zero CSR counters + accum
//   bid (768,7489): fp32 -> bf16 convert of prompt + proj_w
__global__ __launch_bounds__(256) void kA(const float* __restrict__ x,
                                          const float* __restrict__ prompt,
                                          const float* __restrict__ projw,
                                          float* __restrict__ out,
                                          float* __restrict__ xmean,
                                          unsigned short* __restrict__ Abf,
                                          unsigned short* __restrict__ Wbf,
                                          int* __restrict__ cnt,
                                          float* __restrict__ accum) {
    const int bid = blockIdx.x, t = threadIdx.x;
    if (bid < B_ * 3) {
        // ---- mean + copy (accumulation order identical to all prior rounds)
        __shared__ f32x4 red[4][64];
        const int b = bid / 3, seg = bid % 3;
        const int r = t >> 6;                   // wave id 0..3 = row phase
        const int c = t & 63;
        const int c4 = seg * 64 + c;            // float4 column 0..191
        const f32x4* xin  = (const f32x4*)x   + (size_t)b * (N_ * 192) + c4;
        f32x4*       outb = (f32x4*)out       + (size_t)b * (OUTROWS * 192) + c4;
        float sx = 0.f, sy = 0.f, sz = 0.f, sw = 0.f;
        #pragma unroll 7
        for (int n = r; n < 196; n += 4) {
            f32x4 v = __builtin_nontemporal_load(&xin[(size_t)n * 192]);
            sx += v.x; sy += v.y; sz += v.z; sw += v.w;
            int orow = (n == 0) ? 0 : (64 + n);
            __builtin_nontemporal_store(v, &outb[(size_t)orow * 192]);
        }
        if (r == 0) {                           // row 196 remainder
            f32x4 v = __builtin_nontemporal_load(&xin[(size_t)196 * 192]);
            sx += v.x; sy += v.y; sz += v.z; sw += v.w;
            __builtin_nontemporal_store(v, &outb[(size_t)260 * 192]);
        }
        f32x4 s; s.x = sx; s.y = sy; s.z = sz; s.w = sw;
        red[r][c] = s;
        __syncthreads();
        if (r == 0) {
            f32x4 a = red[0][c], b2 = red[1][c], c2 = red[2][c], d = red[3][c];
            const float inv = 1.0f / (float)N_;
            f32x4 m;
            m.x = (a.x + b2.x + c2.x + d.x) * inv;
            m.y = (a.y + b2.y + c2.y + d.y) * inv;
            m.z = (a.z + b2.z + c2.z + d.z) * inv;
            m.w = (a.w + b2.w + c2.w + d.w) * inv;
            ((f32x4*)xmean)[b * 192 + c4] = m;
        }
    } else if (bid == B_ * 3) {
        // ---- zero CSR counters + accumulator (ws is poisoned each iter) ----
        ((f32x4*)cnt)[t] = f32x4{0.f, 0.f, 0.f, 0.f};   // 256*16B = 4KB
        if (t == 0) accum[0] = 0.0f;
    } else {
        // ---- bf16 convert: prompt then proj_w ----
        int i4 = (bid - (B_ * 3 + 1)) * 256 + t;  // 0 .. 1720319
        float4 v; unsigned short* d;
        if (i4 < (PROWS * C_ / 4)) {
            v = ((const float4*)prompt)[i4];
            d = Abf + (size_t)i4 * 4;
        } else {
            int j4 = i4 - PROWS * C_ / 4;
            v = ((const float4*)projw)[j4];
            d = Wbf + (size_t)j4 * 4;
        }
        ushort4 o; o.x = f2bf(v.x); o.y = f2bf(v.y); o.z = f2bf(v.z); o.w = f2bf(v.w);
        *(ushort4*)d = o;
    }
}

// ---------------- Kernel S: similarity GEMM (with in-kernel norms) ----------
// 256 blocks; sim = (xmean @ pkey^T) * invx[m] * invp[n]; norms computed from
// the very elements staged into LDS (proven R3-R5, argmax-invariant factoring).
__global__ __launch_bounds__(256) void kS(const float* __restrict__ xmean,
                                          const float* __restrict__ pkey,
                                          float* __restrict__ sim) {
    __shared__ float As3[32][36];
    __shared__ float Bs3[32][36];
    __shared__ float sqA[32*8];
    __shared__ float sqB[32*8];
    __shared__ float invs[64];
    const int bid = blockIdx.x, t = threadIdx.x;
    const int m0 = (bid >> 5) * 32, n0 = (bid & 31) * 32;
    const int lrow = t >> 3, lc = (t & 7) * 4;
    const int ty = t >> 4, tx = t & 15;
    float a00 = 0.f, a01 = 0.f, a10 = 0.f, a11 = 0.f;
    float sqa = 0.f, sqb = 0.f;
    float4 va = *(const float4*)&xmean[(size_t)(m0 + lrow) * C_ + lc];
    float4 vb = *(const float4*)&pkey [(size_t)(n0 + lrow) * C_ + lc];
    for (int k0 = 0; k0 < C_; k0 += 32) {
        __syncthreads();
        *(float4*)&As3[lrow][lc] = va;
        *(float4*)&Bs3[lrow][lc] = vb;
        sqa += va.x*va.x + va.y*va.y + va.z*va.z + va.w*va.w;
        sqb += vb.x*vb.x + vb.y*vb.y + vb.z*vb.z + vb.w*vb.w;
        __syncthreads();
        if (k0 + 32 < C_) {                     // prefetch next tile
            va = *(const float4*)&xmean[(size_t)(m0 + lrow) * C_ + k0 + 32 + lc];
            vb = *(const float4*)&pkey [(size_t)(n0 + lrow) * C_ + k0 + 32 + lc];
        }
        #pragma unroll
        for (int kk = 0; kk < 32; kk += 4) {
            float4 A0 = *(const float4*)&As3[ty*2][kk];
            float4 A1 = *(const float4*)&As3[ty*2+1][kk];
            float4 B0 = *(const float4*)&Bs3[tx*2][kk];
            float4 B1 = *(const float4*)&Bs3[tx*2+1][kk];
            a00 += A0.x*B0.x; a00 += A0.y*B0.y; a00 += A0.z*B0.z; a00 += A0.w*B0.w;
            a01 += A0.x*B1.x; a01 += A0.y*B1.y; a01 += A0.z*B1.z; a01 += A0.w*B1.w;
            a10 += A1.x*B0.x; a10 += A1.y*B0.y; a10 += A1.z*B0.z; a10 += A1.w*B0.w;
            a11 += A1.x*B1.x; a11 += A1.y*B1.y; a11 += A1.z*B1.z; a11 += A1.w*B1.w;
        }
    }
    sqA[lrow*8 + (t & 7)] = sqa;
    sqB[lrow*8 + (t & 7)] = sqb;
    __syncthreads();
    if (t < 64) {
        const float* s = (t < 32) ? sqA : sqB;
        const int rr = t & 31;
        float tot = 0.f;
        #pragma unroll
        for (int j = 0; j < 8; ++j) tot += s[rr*8 + j];
        invs[t] = 1.0f / sqrtf(fmaxf(tot, 1e-12f));
    }
    __syncthreads();
    const float im0 = invs[ty*2], im1 = invs[ty*2 + 1];
    const float ip0 = invs[32 + tx*2], ip1 = invs[32 + tx*2 + 1];
    sim[(size_t)(m0 + ty*2    ) * POOL_ + n0 + tx*2    ] = a00 * im0 * ip0;
    sim[(size_t)(m0 + ty*2    ) * POOL_ + n0 + tx*2 + 1] = a01 * im0 * ip1;
    sim[(size_t)(m0 + ty*2 + 1) * POOL_ + n0 + tx*2    ] = a10 * im1 * ip0;
    sim[(size_t)(m0 + ty*2 + 1) * POOL_ + n0 + tx*2 + 1] = a11 * im1 * ip1;
}

// ---------------- Kernel T: top-8 per row + inverted CSR index --------------
// One block per row; lax.top_k tie semantics (proven). After selection,
// 8 threads append (b,k) to the per-pool-entry CSR via device-scope atomics.
__global__ __launch_bounds__(256) void kT(const float* __restrict__ sim,
                                          int* __restrict__ cnt,
                                          int* __restrict__ entries,
                                          float* __restrict__ accum) {
    __shared__ float vals[POOL_];
    __shared__ float wv[4];
    __shared__ int   wi[4];
    __shared__ int   sidx[TOPK_];
    const int b = blockIdx.x, t = threadIdx.x;
    const int wave = t >> 6;
    #pragma unroll
    for (int i = 0; i < 4; ++i) vals[t + 256*i] = sim[(size_t)b * POOL_ + t + 256*i];
    __syncthreads();
    float sumv = 0.0f;
    for (int k = 0; k < TOPK_; ++k) {
        float bv = -FLT_MAX; int bi = POOL_;
        #pragma unroll
        for (int i = 0; i < 4; ++i) {          // ascending n -> ties keep lower idx
            int n = t + 256*i;
            float v = vals[n];
            if (v > bv) { bv = v; bi = n; }
        }
        #pragma unroll
        for (int off = 32; off > 0; off >>= 1) {
            float v2 = __shfl_down(bv, off);
            int   i2 = __shfl_down(bi, off);
            if (v2 > bv || (v2 == bv && i2 < bi)) { bv = v2; bi = i2; }
        }
        if ((t & 63) == 0) { wv[wave] = bv; wi[wave] = bi; }
        __syncthreads();
        if (t == 0) {
            float fv = wv[0]; int fi = wi[0];
            #pragma unroll
            for (int w = 1; w < 4; ++w) {
                float v2 = wv[w]; int i2 = wi[w];
                if (v2 > fv || (v2 == fv && i2 < fi)) { fv = v2; fi = i2; }
            }
            sidx[k] = fi;
            sumv += fv;
            vals[fi] = -FLT_MAX;
        }
        __syncthreads();                       // publishes sidx[k]
    }
    if (t < TOPK_) {                           // CSR append (order irrelevant)
        const int p = sidx[t];
        const int pos = atomicAdd(&cnt[p], 1);
        entries[(p << 8) + pos] = (b << 3) | t;
    }
    if (t == 0) atomicAdd(accum, sumv);
}

// ---------------- Kernel G: projection GEMM + scatter epilogue + scalar -----
// val = Abf @ Wbf^T + bias + prompt for pool rows whose entry was selected;
// values scatter directly to every out row that selected the entry (CSR).
// Blocks whose 8 pool entries all have cnt==0 exit before the MFMA loop.
__global__ __launch_bounds__(256) void kG(const unsigned short* __restrict__ A,
                                          const unsigned short* __restrict__ W,
                                          const float* __restrict__ bias,
                                          const float* __restrict__ resid,
                                          const int* __restrict__ cnt,
                                          const int* __restrict__ entries,
                                          const float* __restrict__ accum,
                                          float* __restrict__ out) {
    __shared__ short As5[2][64*32];
    __shared__ short Bs5[2][128*32];
    const int tid = threadIdx.x;
    const int bid = blockIdx.x;
    if (bid == 0 && tid == 0)                  // accum complete (stream order)
        out[(size_t)B_ * OUTROWS * C_] = accum[0] * (1.0f / (float)B_);

    const int m0 = (bid / 6) * 64, n0 = (bid % 6) * 128;

    // ---- early exit: none of this block's 8 pool entries selected ----
    const int pbase = m0 >> 3;
    int anyhit = 0;
    #pragma unroll
    for (int e = 0; e < 8; ++e) anyhit |= cnt[pbase + e];
    if (anyhit == 0) return;                   // uniform across block

    const int wave = tid >> 6, lane = tid & 63;
    const int quad = lane >> 4, lr = lane & 15;
    const int srow = tid >> 2;                  // 0..63
    const int scol = (tid & 3) * 8;             // 0,8,16,24

    f32x4 acc[4][2] = {};

    auto stage = [&](int buf, int kt) {
        const int k0 = kt * 32;
        __builtin_amdgcn_global_load_lds(
            (const __attribute__((address_space(1))) void*)&A[(size_t)(m0 + srow) * C_ + k0 + scol],
            (__attribute__((address_space(3))) void*)&As5[buf][srow*32 + scol], 16, 0, 0);
        __builtin_amdgcn_global_load_lds(
            (const __attribute__((address_space(1))) void*)&W[(size_t)(n0 + srow) * C_ + k0 + scol],
            (__attribute__((address_space(3))) void*)&Bs5[buf][srow*32 + scol], 16, 0, 0);
        __builtin_amdgcn_global_load_lds(
            (const __attribute__((address_space(1))) void*)&W[(size_t)(n0 + 64 + srow) * C_ + k0 + scol],
            (__attribute__((address_space(3))) void*)&Bs5[buf][(64 + srow)*32 + scol], 16, 0, 0);
    };
    auto compute = [&](int buf) {
        short8_t af[4], bf[2];
        #pragma unroll
        for (int i = 0; i < 4; ++i)
            af[i] = *(const short8_t*)&As5[buf][(i*16 + lr)*32 + quad*8];
        #pragma unroll
        for (int j = 0; j < 2; ++j)
            bf[j] = *(const short8_t*)&Bs5[buf][(wave*32 + j*16 + lr)*32 + quad*8];
        #pragma unroll
        for (int i = 0; i < 4; ++i)
            #pragma unroll
            for (int j = 0; j < 2; ++j)
                acc[i][j] = __builtin_amdgcn_mfma_f32_16x16x32_bf16(af[i], bf[j], acc[i][j], 0, 0, 0);
    };

    stage(0, 0);
    __syncthreads();
    int cur = 0;
    for (int kt = 0; kt < 23; ++kt) {
        stage(cur ^ 1, kt + 1);                 // overlap next stage with compute
        compute(cur);
        __syncthreads();
        cur ^= 1;
    }
    compute(cur);

    // ---- scatter epilogue ----
    const float bn0 = bias[n0 + wave*32 + lr];
    const float bn1 = bias[n0 + wave*32 + 16 + lr];
    const int ncol = n0 + wave*32 + lr;         // j stride = 16
    #pragma unroll
    for (int i = 0; i < 4; ++i) {
        const int m  = m0 + i*16 + quad*4;      // rows m..m+3
        const int p  = m >> 3;                  // pool entry (uniform over r)
        const int lb = m & 7;                   // prompt-slot for r=0 (r adds)
        const int c  = cnt[p];
        if (c != 0) {
            float vals[2][4];
            #pragma unroll
            for (int r = 0; r < 4; ++r) {
                vals[0][r] = acc[i][0][r] + bn0 + resid[(size_t)(m + r) * C_ + ncol];
                vals[1][r] = acc[i][1][r] + bn1 + resid[(size_t)(m + r) * C_ + ncol + 16];
            }
            for (int h = 0; h < c; ++h) {
                const int bk = entries[(p << 8) + h];
                const size_t obase =
                    (size_t)((bk >> 3) * OUTROWS + 1 + (bk & 7) * 8 + lb) * C_ + ncol;
                #pragma unroll
                for (int r = 0; r < 4; ++r) {
                    out[obase + (size_t)r * C_]      = vals[0][r];
                    out[obase + (size_t)r * C_ + 16] = vals[1][r];
                }
            }
        }
    }
}

// ---------------- launcher ---------------------------------------------------
extern "C" void kernel_launch(void* const* d_in, const int* in_sizes, int n_in,
                              void* d_out, int out_size, void* d_ws, size_t ws_size,
                              hipStream_t stream) {
    const float* x_embed = (const float*)d_in[0];
    const float* prompt  = (const float*)d_in[1];
    const float* pkey    = (const float*)d_in[2];
    const float* projw   = (const float*)d_in[3];
    const float* projb   = (const float*)d_in[4];
    float* out = (float*)d_out;
    char* ws = (char*)d_ws;

    float*          xmean   = (float*)(ws + OFF_XMEAN);
    float*          sim     = (float*)(ws + OFF_SIM);
    float*          acc     = (float*)(ws + OFF_ACC);
    int*            cnt     = (int*)(ws + OFF_CNT);
    int*            ent     = (int*)(ws + OFF_ENT);
    unsigned short* Abf     = (unsigned short*)(ws + OFF_ABF);
    unsigned short* Wbf     = (unsigned short*)(ws + OFF_WBF);

    const int convBlocks = (PROWS * C_ / 4 + 768 * 768 / 4) / 256;   // 6720
    kA<<<B_ * 3 + 1 + convBlocks, 256, 0, stream>>>(x_embed, prompt, projw,
                                                    out, xmean, Abf, Wbf, cnt, acc);
    kS<<<256, 256, 0, stream>>>(xmean, pkey, sim);
    kT<<<B_, 256, 0, stream>>>(sim, cnt, ent, acc);
    kG<<<768, 256, 0, stream>>>(Abf, Wbf, projb, prompt, cnt, ent, acc, out);
}